// Round 5
// baseline (262.242 us; speedup 1.0000x reference)
//
#include <hip/hip_runtime.h>

using v4f = float __attribute__((ext_vector_type(4)));

constexpr int NTOK = 32768;       // 16 * 2048 tokens
constexpr int DIMS = 64;
constexpr int KCODES = 1000;
constexpr int NSPLIT = 4;         // K-splits: 256 codes each (last padded to 1024)
constexpr int CPSPLIT = 256;
constexpr float BIG = 3.4e38f;

// ---------------------------------------------------------------- prep: norms + zero scratch
// thread = (code, d-quarter): 4000 threads, 16 blocks
__global__ void vq_prep(const float* __restrict__ emb, float* __restrict__ norms,
                        float* __restrict__ loss_accum, int* __restrict__ usage,
                        int* __restrict__ counter)
{
    int t = blockIdx.x * 256 + threadIdx.x;
    if (t == 0) { *loss_accum = 0.f; *counter = 0; }
    int c = t >> 2, q = t & 3;
    if (c < KCODES) {
        if (q == 0) usage[c] = 0;
        const float* e = emb + c * DIMS + q * 16;
        float s = 0.f;
        #pragma unroll
        for (int i = 0; i < 4; ++i) {
            v4f v = *reinterpret_cast<const v4f*>(e + i * 4);
            s = fmaf(v[0], v[0], fmaf(v[1], v[1], fmaf(v[2], v[2], fmaf(v[3], v[3], s))));
        }
        s += __shfl_xor(s, 1);   // threads c*4+q are lane-adjacent
        s += __shfl_xor(s, 2);
        if (q == 0) norms[c] = s;
    }
}

// ---------------------------------------------------------------- main argmin
// lane = token: x[64] in VGPRs (loaded once), e/norms wave-uniform -> scalar loads,
// per-lane scalar running argmin. No LDS, no cross-lane ops.
__global__ __launch_bounds__(256) void vq_main(
    const float* __restrict__ x, const float* __restrict__ emb,
    const float* __restrict__ norms,
    float* __restrict__ pval, int* __restrict__ pidx)
{
    const int tid   = threadIdx.x;
    const int split = blockIdx.x >> 7;    // 0..3 ; blocks of same tb differ by 128 (=0 mod 8): same XCD
    const int tb    = blockIdx.x & 127;
    const int token = tb * 256 + tid;     // 256-token tile never crosses a b-boundary
    const int b     = token >> 11;
    const int l     = token & 2047;
    const float* xp = x + ((size_t)b << 17) + l;

    // x for this lane's token: 64 VGPRs, coalesced (lane i -> consecutive l)
    float xv[DIMS];
    #pragma unroll
    for (int d = 0; d < DIMS; ++d) xv[d] = xp[(size_t)d * 2048];

    const int cbase = split * CPSPLIT;
    float minv = BIG;
    int   mini = 0;

    for (int g = 0; g < CPSPLIT / 8; ++g) {          // 32 groups of 8 codes
        const int c0 = cbase + g * 8;
        if (c0 + 8 <= KCODES) {                      // fast path (all but 1 group)
            const float* eg = emb + (size_t)c0 * DIMS;
            float acc[8] = {0.f,0.f,0.f,0.f,0.f,0.f,0.f,0.f};
            #pragma unroll
            for (int d4 = 0; d4 < 16; ++d4) {
                #pragma unroll
                for (int c = 0; c < 8; ++c) {
                    v4f ev = *reinterpret_cast<const v4f*>(eg + c * DIMS + d4 * 4); // uniform -> s_load
                    #pragma unroll
                    for (int k = 0; k < 4; ++k)
                        acc[c] = fmaf(xv[d4 * 4 + k], ev[k], acc[c]);
                }
            }
            #pragma unroll
            for (int c = 0; c < 8; ++c) {            // ascending c: strict < keeps first min
                float dist = fmaf(-2.f, acc[c], norms[c0 + c]);
                if (dist < minv) { minv = dist; mini = c0 + c; }
            }
        } else if (c0 < KCODES) {                    // partial tail group
            for (int c = 0; c < 8; ++c) {
                int gc = c0 + c;
                if (gc >= KCODES) break;
                const float* ep = emb + (size_t)gc * DIMS;
                float a = 0.f;
                #pragma unroll
                for (int d4 = 0; d4 < 16; ++d4) {
                    v4f ev = *reinterpret_cast<const v4f*>(ep + d4 * 4);
                    #pragma unroll
                    for (int k = 0; k < 4; ++k) a = fmaf(xv[d4 * 4 + k], ev[k], a);
                }
                float dist = fmaf(-2.f, a, norms[gc]);
                if (dist < minv) { minv = dist; mini = gc; }
            }
        }
        // c0 >= KCODES: fully padded group, nothing to do
    }

    pval[split * NTOK + token] = minv;   // coalesced
    pidx[split * NTOK + token] = mini;
}

// ---------------------------------------------------------------- merge + gather + STE + loss + usage
// 2D: block = 64 tokens x 4 dim-groups, 512 blocks. NO fence, NO ticket.
__global__ __launch_bounds__(256) void vq_output(
    const float* __restrict__ x, const float* __restrict__ emb,
    const float* __restrict__ pval, const int* __restrict__ pidx,
    float* __restrict__ out, float* __restrict__ idx_f,
    float* __restrict__ loss_accum, int* __restrict__ usage)
{
    const int tid   = threadIdx.x;
    const int ll    = tid & 63;
    const int dg    = tid >> 6;
    const int token = blockIdx.x * 64 + ll;

    float bv = pval[token];
    int   bi = pidx[token];
    #pragma unroll
    for (int s = 1; s < NSPLIT; ++s) {               // ascending split: strict < keeps lowest idx
        float v  = pval[s * NTOK + token];
        int   i2 = pidx[s * NTOK + token];
        if (v < bv) { bv = v; bi = i2; }
    }
    if (dg == 0) {
        idx_f[token] = (float)bi;
        atomicOr(&usage[bi], 1);                     // device-scope atomic: XCD-safe
    }

    const int b = token >> 11, l = token & 2047;
    const float* xb = x   + ((size_t)b << 17) + l + (size_t)(dg * 16) * 2048;
    float*       ob = out + ((size_t)b << 17) + l + (size_t)(dg * 16) * 2048;
    const float* e  = emb + (size_t)bi * DIMS + dg * 16;

    float lsum = 0.f;
    #pragma unroll
    for (int q4 = 0; q4 < 4; ++q4) {
        v4f q = *reinterpret_cast<const v4f*>(e + q4 * 4);
        #pragma unroll
        for (int k = 0; k < 4; ++k) {
            const int d = q4 * 4 + k;
            float xv   = xb[(size_t)d * 2048];
            float diff = q[k] - xv;                  // quantized - inputs
            lsum = fmaf(diff, diff, lsum);
            ob[(size_t)d * 2048] = xv + diff;        // exact STE forward rounding
        }
    }

    #pragma unroll
    for (int off = 32; off >= 1; off >>= 1) lsum += __shfl_xor(lsum, off);
    __shared__ float bsum[4];
    if ((tid & 63) == 0) bsum[tid >> 6] = lsum;
    __syncthreads();
    if (tid == 0) atomicAdd(loss_accum, bsum[0] + bsum[1] + bsum[2] + bsum[3]);
}

// ---------------------------------------------------------------- finalize scalars (tiny, separate)
__global__ void vq_finalize(const float* __restrict__ loss_accum, const int* __restrict__ usage,
                            float* __restrict__ o_scalars)
{
    __shared__ int wsum[16];
    int tid = threadIdx.x;   // 1024 threads
    int c = (tid < KCODES && usage[tid]) ? 1 : 0;
    #pragma unroll
    for (int off = 32; off >= 1; off >>= 1) c += __shfl_xor(c, off);
    if ((tid & 63) == 0) wsum[tid >> 6] = c;
    __syncthreads();
    if (tid == 0) {
        int total = 0;
        #pragma unroll
        for (int i = 0; i < 16; ++i) total += wsum[i];
        float m = *loss_accum / 2097152.0f;          // mean over B*L*D
        o_scalars[0] = 11.0f * m;                    // q_latent + 10 * e_latent
        o_scalars[1] = (float)total;
    }
}

// ---------------------------------------------------------------- launch
extern "C" void kernel_launch(void* const* d_in, const int* in_sizes, int n_in,
                              void* d_out, int out_size, void* d_ws, size_t ws_size,
                              hipStream_t stream)
{
    const float* x   = (const float*)d_in[0];   // [16, 64, 2048]
    const float* emb = (const float*)d_in[1];   // [1000, 64]

    float* o       = (float*)d_out;
    float* out     = o;                 // 2097152 floats, [B, D, L]
    float* o_scal  = o + 2097152;       // loss, usage
    float* o_idx   = o + 2097154;       // 32768 floats

    char*  ws         = (char*)d_ws;
    float* loss_accum = (float*)(ws);
    int*   counter    = (int*)(ws + 8);
    int*   usage      = (int*)(ws + 64);
    float* norms      = (float*)(ws + 4160);
    float* pval       = (float*)(ws + 8192);
    int*   pidx       = (int*)(ws + 8192 + NSPLIT * NTOK * sizeof(float));
    // total ws use: ~1.03 MB

    vq_prep<<<16, 256, 0, stream>>>(emb, norms, loss_accum, usage, counter);
    vq_main<<<NSPLIT * 128, 256, 0, stream>>>(x, emb, norms, pval, pidx);
    vq_output<<<NTOK / 64, 256, 0, stream>>>(x, emb, pval, pidx, out, o_idx, loss_accum, usage);
    vq_finalize<<<1, 1024, 0, stream>>>(loss_accum, usage, o_scal);
}

// Round 6
// 167.171 us; speedup vs baseline: 1.5687x; 1.5687x over previous
//
#include <hip/hip_runtime.h>

using v4f = float __attribute__((ext_vector_type(4)));

constexpr int NTOK = 32768;       // 16 * 2048 tokens
constexpr int DIMS = 64;
constexpr int KCODES = 1000;
constexpr int NSPLIT = 8;         // 128 codes per split (split 7: 896..999 + pad)
constexpr int CPSPLIT = 128;
constexpr float BIG = 3.4e38f;

// ---------------------------------------------------------------- main argmin
// lane = token: x[64] pinned in VGPRs (loaded once); e wave-uniform -> scalar
// loads feeding v_fma directly; per-block LDS norms (exact prep fp ordering);
// 4-code groups (4 indep FMA chains; 1000%4==0 so no straddling tail).
__global__ __launch_bounds__(256, 4) void vq_main(
    const float* __restrict__ x, const float* __restrict__ emb,
    float* __restrict__ pval, int* __restrict__ pidx,
    float* __restrict__ loss_accum, int* __restrict__ usage)
{
    __shared__ float ns[CPSPLIT];

    const int tid   = threadIdx.x;
    const int split = blockIdx.x >> 7;     // 0..7; same token-tile across splits -> same XCD (mod 8)
    const int tb    = blockIdx.x & 127;
    const int token = tb * 256 + tid;      // 256-token tile never crosses a b-boundary
    const int b     = token >> 11;
    const int l     = token & 2047;
    const float* xp = x + ((size_t)b << 17) + l;
    const int cbase = split * CPSPLIT;

    // zero-init scratch consumed by vq_output (ws is poisoned 0xAA each launch)
    if (blockIdx.x == 0) {
        for (int u = tid; u < KCODES; u += 256) usage[u] = 0;
        if (tid == 0) *loss_accum = 0.f;
    }

    // block-local norms for this split's codes — bit-identical fp order to old prep:
    // per-16-float FMA nest, then pairwise combine
    if (tid < CPSPLIT) {
        int g = cbase + tid;
        float nv = BIG;                    // padded codes never win
        if (g < KCODES) {
            const float* e = emb + (size_t)g * DIMS;
            float sq[4];
            #pragma unroll
            for (int q = 0; q < 4; ++q) {
                float s = 0.f;
                #pragma unroll
                for (int i = 0; i < 4; ++i) {
                    v4f v = *reinterpret_cast<const v4f*>(e + q * 16 + i * 4);
                    s = fmaf(v[0], v[0], fmaf(v[1], v[1], fmaf(v[2], v[2], fmaf(v[3], v[3], s))));
                }
                sq[q] = s;
            }
            nv = (sq[0] + sq[1]) + (sq[2] + sq[3]);
        }
        ns[tid] = nv;
    }

    // x for this lane's token: 64 VGPRs, coalesced, loaded ONCE — then pinned so the
    // compiler cannot rematerialize the loads inside the loop (r5 failure: VGPR=44)
    float xv[DIMS];
    #pragma unroll
    for (int d = 0; d < DIMS; ++d) xv[d] = xp[(size_t)d * 2048];
    #pragma unroll
    for (int d = 0; d < DIMS; ++d) asm volatile("" : "+v"(xv[d]));

    __syncthreads();

    float minv = BIG;
    int   mini = 0;

    for (int g4 = 0; g4 < CPSPLIT / 4; ++g4) {
        const int c0 = cbase + g4 * 4;
        if (c0 >= KCODES) break;           // uniform: only split 7's padded groups
        const float* eg = emb + (size_t)c0 * DIMS;
        float acc[4] = {0.f, 0.f, 0.f, 0.f};
        #pragma unroll
        for (int d4 = 0; d4 < 16; ++d4) {
            #pragma unroll
            for (int c = 0; c < 4; ++c) {
                v4f ev = *reinterpret_cast<const v4f*>(eg + c * DIMS + d4 * 4); // uniform -> s_load
                #pragma unroll
                for (int k = 0; k < 4; ++k)
                    acc[c] = fmaf(xv[d4 * 4 + k], ev[k], acc[c]);
            }
        }
        #pragma unroll
        for (int c = 0; c < 4; ++c) {      // ascending c: strict < keeps first min
            float dist = fmaf(-2.f, acc[c], ns[g4 * 4 + c]);
            if (dist < minv) { minv = dist; mini = c0 + c; }
        }
    }

    pval[split * NTOK + token] = minv;     // coalesced
    pidx[split * NTOK + token] = mini;
}

// ---------------------------------------------------------------- merge + gather + STE + loss + usage
// 2D: block = 64 tokens x 4 dim-groups, 512 blocks
__global__ __launch_bounds__(256) void vq_output(
    const float* __restrict__ x, const float* __restrict__ emb,
    const float* __restrict__ pval, const int* __restrict__ pidx,
    float* __restrict__ out, float* __restrict__ idx_f,
    float* __restrict__ loss_accum, int* __restrict__ usage)
{
    const int tid   = threadIdx.x;
    const int ll    = tid & 63;
    const int dg    = tid >> 6;
    const int token = blockIdx.x * 64 + ll;

    float bv = pval[token];
    int   bi = pidx[token];
    #pragma unroll
    for (int s = 1; s < NSPLIT; ++s) {     // ascending split: strict < keeps lowest idx
        float v  = pval[s * NTOK + token];
        int   i2 = pidx[s * NTOK + token];
        if (v < bv) { bv = v; bi = i2; }
    }
    if (dg == 0) {
        idx_f[token] = (float)bi;
        atomicOr(&usage[bi], 1);           // device-scope atomic: XCD-safe
    }

    const int b = token >> 11, l = token & 2047;
    const float* xb = x   + ((size_t)b << 17) + l + (size_t)(dg * 16) * 2048;
    float*       ob = out + ((size_t)b << 17) + l + (size_t)(dg * 16) * 2048;
    const float* e  = emb + (size_t)bi * DIMS + dg * 16;

    float lsum = 0.f;
    #pragma unroll
    for (int q4 = 0; q4 < 4; ++q4) {
        v4f q = *reinterpret_cast<const v4f*>(e + q4 * 4);
        #pragma unroll
        for (int k = 0; k < 4; ++k) {
            const int d = q4 * 4 + k;
            float xvv  = xb[(size_t)d * 2048];
            float diff = q[k] - xvv;               // quantized - inputs
            lsum = fmaf(diff, diff, lsum);
            ob[(size_t)d * 2048] = xvv + diff;     // exact STE forward rounding
        }
    }

    #pragma unroll
    for (int off = 32; off >= 1; off >>= 1) lsum += __shfl_xor(lsum, off);
    __shared__ float bsum[4];
    if ((tid & 63) == 0) bsum[tid >> 6] = lsum;
    __syncthreads();
    if (tid == 0) atomicAdd(loss_accum, bsum[0] + bsum[1] + bsum[2] + bsum[3]);
}

// ---------------------------------------------------------------- finalize scalars (tiny)
__global__ void vq_finalize(const float* __restrict__ loss_accum, const int* __restrict__ usage,
                            float* __restrict__ o_scalars)
{
    __shared__ int wsum[16];
    int tid = threadIdx.x;   // 1024 threads
    int c = (tid < KCODES && usage[tid]) ? 1 : 0;
    #pragma unroll
    for (int off = 32; off >= 1; off >>= 1) c += __shfl_xor(c, off);
    if ((tid & 63) == 0) wsum[tid >> 6] = c;
    __syncthreads();
    if (tid == 0) {
        int total = 0;
        #pragma unroll
        for (int i = 0; i < 16; ++i) total += wsum[i];
        float m = *loss_accum / 2097152.0f;        // mean over B*L*D
        o_scalars[0] = 11.0f * m;                  // q_latent + 10 * e_latent
        o_scalars[1] = (float)total;
    }
}

// ---------------------------------------------------------------- launch
extern "C" void kernel_launch(void* const* d_in, const int* in_sizes, int n_in,
                              void* d_out, int out_size, void* d_ws, size_t ws_size,
                              hipStream_t stream)
{
    const float* x   = (const float*)d_in[0];   // [16, 64, 2048]
    const float* emb = (const float*)d_in[1];   // [1000, 64]

    float* o       = (float*)d_out;
    float* out     = o;                 // 2097152 floats, [B, D, L]
    float* o_scal  = o + 2097152;       // loss, usage
    float* o_idx   = o + 2097154;       // 32768 floats

    char*  ws         = (char*)d_ws;
    float* loss_accum = (float*)(ws);
    int*   usage      = (int*)(ws + 64);
    float* pval       = (float*)(ws + 8192);
    int*   pidx       = (int*)(ws + 8192 + NSPLIT * NTOK * sizeof(float));
    // total ws use: ~2.06 MB

    vq_main<<<NSPLIT * 128, 256, 0, stream>>>(x, emb, pval, pidx, loss_accum, usage);
    vq_output<<<NTOK / 64, 256, 0, stream>>>(x, emb, pval, pidx, out, o_idx, loss_accum, usage);
    vq_finalize<<<1, 1024, 0, stream>>>(loss_accum, usage, o_scal);
}